// Round 4
// baseline (259.005 us; speedup 1.0000x reference)
//
#include <hip/hip_runtime.h>
#include <hip/hip_bf16.h>

typedef __attribute__((ext_vector_type(8))) short bf16x8;
typedef __attribute__((ext_vector_type(4))) short bf16x4;
typedef __attribute__((ext_vector_type(4))) float f32x4;

static __device__ __forceinline__ __hip_bfloat16 f2b(float f) {
    return __float2bfloat16(f);
}
static __device__ __forceinline__ unsigned pack2(float a, float b) {
    unsigned ua = (unsigned)__bfloat16_as_ushort(__float2bfloat16(a));
    unsigned ub = (unsigned)__bfloat16_as_ushort(__float2bfloat16(b));
    return ua | (ub << 16);
}
static __device__ __forceinline__ float exp2fast(float x) {
    return __builtin_amdgcn_exp2f(x);
}

// ---------------------------------------------------------------------------
// f32 -> bf16 elementwise convert
// ---------------------------------------------------------------------------
__global__ __launch_bounds__(256) void k_f32_to_bf16(
    const float* __restrict__ in, __hip_bfloat16* __restrict__ out, int n4)
{
    int i = blockIdx.x * blockDim.x + threadIdx.x;
    int stride = gridDim.x * blockDim.x;
    for (; i < n4; i += stride) {
        float4 v = reinterpret_cast<const float4*>(in)[i];
        __hip_bfloat16* o = out + 4 * (size_t)i;
        o[0] = f2b(v.x); o[1] = f2b(v.y); o[2] = f2b(v.z); o[3] = f2b(v.w);
    }
}

// ---------------------------------------------------------------------------
// f32 [R][Cn] -> bf16 [Cn][R] tiled transpose
// ---------------------------------------------------------------------------
__global__ __launch_bounds__(256) void k_transpose_f32_bf16(
    const float* __restrict__ in, __hip_bfloat16* __restrict__ out, int R, int Cn)
{
    __shared__ float tile[32][33];
    const int c0 = blockIdx.x * 32, r0 = blockIdx.y * 32;
    const int tx = threadIdx.x & 31, ty = threadIdx.x >> 5;
#pragma unroll
    for (int i = 0; i < 32; i += 8)
        tile[ty + i][tx] = in[(size_t)(r0 + ty + i) * Cn + c0 + tx];
    __syncthreads();
#pragma unroll
    for (int i = 0; i < 32; i += 8)
        out[(size_t)(c0 + ty + i) * R + r0 + tx] = f2b(tile[tx][ty + i]);
}

// ---------------------------------------------------------------------------
// GEMM: C[M][N] = A[M][K] @ Bt[N][K]^T + bias  (m97 structure)
// EPI=0: qkv epilogue. Q is pre-scaled by (1/8)*log2(e) for exp2-domain
// softmax in k_attn.
// ---------------------------------------------------------------------------
#define QSCALE 0.1803368801111f   // 0.125 * log2(e)

template <int EPI>
__global__ __launch_bounds__(256) void k_gemm_bt(
    const __hip_bfloat16* __restrict__ A,
    const __hip_bfloat16* __restrict__ Bt,
    const float* __restrict__ bias,
    int K, int Nn,
    float* __restrict__ outf,
    __hip_bfloat16* __restrict__ Qb,
    __hip_bfloat16* __restrict__ Kb,
    __hip_bfloat16* __restrict__ Vt)
{
    __shared__ __hip_bfloat16 As[128][64];
    __shared__ __hip_bfloat16 Bs[128][64];

    const int tid = threadIdx.x;
    const int lane = tid & 63;
    const int wid = tid >> 6;
    const int wm = wid >> 1, wn = wid & 1;
    const int m0 = blockIdx.y * 128, n0 = blockIdx.x * 128;
    const int l15 = lane & 15, lg = lane >> 4;

    f32x4 acc[4][4] = {};

    const int srow = tid >> 3;
    const int scol = (tid & 7) * 8;

    for (int k0 = 0; k0 < K; k0 += 64) {
#pragma unroll
        for (int i = 0; i < 4; ++i) {
            int r = srow + 32 * i;
            __builtin_amdgcn_global_load_lds(
                (const __attribute__((address_space(1))) void*)(A + (size_t)(m0 + r) * K + k0 + scol),
                (__attribute__((address_space(3))) void*)(&As[r][scol]), 16, 0, 0);
        }
#pragma unroll
        for (int i = 0; i < 4; ++i) {
            int r = srow + 32 * i;
            __builtin_amdgcn_global_load_lds(
                (const __attribute__((address_space(1))) void*)(Bt + (size_t)(n0 + r) * K + k0 + scol),
                (__attribute__((address_space(3))) void*)(&Bs[r][scol]), 16, 0, 0);
        }
        __syncthreads();
#pragma unroll
        for (int c = 0; c < 2; ++c) {
            bf16x8 a[4], bb[4];
#pragma unroll
            for (int m = 0; m < 4; ++m)
                a[m] = *(const bf16x8*)&As[wm * 64 + m * 16 + l15][c * 32 + lg * 8];
#pragma unroll
            for (int n = 0; n < 4; ++n)
                bb[n] = *(const bf16x8*)&Bs[wn * 64 + n * 16 + l15][c * 32 + lg * 8];
#pragma unroll
            for (int m = 0; m < 4; ++m)
#pragma unroll
                for (int n = 0; n < 4; ++n)
                    acc[m][n] = __builtin_amdgcn_mfma_f32_16x16x32_bf16(a[m], bb[n], acc[m][n], 0, 0, 0);
        }
        __syncthreads();
    }

#pragma unroll
    for (int m = 0; m < 4; ++m) {
        const int row = m0 + wm * 64 + m * 16 + lg * 4;
#pragma unroll
        for (int n = 0; n < 4; ++n) {
            const int col = n0 + wn * 64 + n * 16 + l15;
            const float bv = bias[col];
#pragma unroll
            for (int r = 0; r < 4; ++r) {
                float val = acc[m][n][r] + bv;
                const int rr = row + r;
                if (EPI == 0) {
                    const int sec = col >> 10, cw = col & 1023;
                    const int hh = cw >> 6, d = cw & 63;
                    const int bq = rr >> 11, t = rr & 2047;
                    const int bh = bq * 16 + hh;
                    if (sec == 0)
                        Qb[((size_t)bh * 2048 + t) * 64 + d] = f2b(val * QSCALE);
                    else if (sec == 1)
                        Kb[((size_t)bh * 2048 + t) * 64 + d] = f2b(val);
                    else
                        Vt[((size_t)bh * 64 + d) * 2048 + t] = f2b(val);
                } else {
                    outf[(size_t)rr * Nn + col] = val;
                }
            }
        }
    }
}

// ---------------------------------------------------------------------------
// Causal flash attention v4 — swapped-operand MFMA, exp2 domain, defer-max,
// K reg double-buffer pipeline, unmasked full-step fast path.
// Q,K: [BH][T][64] bf16 (Q pre-scaled by QSCALE), Vt: [BH][64][T] bf16.
// S = mfma(K,Q):  row = key (in-lane lg*4+r), col = q (l15)
// O = mfma(Vt,P): row = d   (in-lane lg*4+r), col = q (l15)
// ---------------------------------------------------------------------------
#define DEFER_THR 4.0f

__global__ __launch_bounds__(256, 2) void k_attn(
    const __hip_bfloat16* __restrict__ Qb,
    const __hip_bfloat16* __restrict__ Kb,
    const __hip_bfloat16* __restrict__ Vt,
    __hip_bfloat16* __restrict__ att)
{
    __shared__ __hip_bfloat16 P_lds[4][2][16 * 64];
    const int tid = threadIdx.x, lane = tid & 63, wid = tid >> 6;
    const int lid = blockIdx.x;
    const int xcd = lid & 7, j = lid >> 3;
    const int jj = j >> 2;
    const int tile = (jj < 8) ? (15 - jj) : (jj - 8);   // heavy tiles first
    const int bh = xcd * 4 + (j & 3);
    const int q0 = tile * 128;
    const int qw = q0 + wid * 32;
    const int l15 = lane & 15, lg = lane >> 4;
    const int swz = (l15 & 7) << 3;

    const __hip_bfloat16* Qbase = Qb + (size_t)bh * 2048 * 64;
    const __hip_bfloat16* Kbase = Kb + (size_t)bh * 2048 * 64;
    const __hip_bfloat16* Vbase = Vt + (size_t)bh * 64 * 2048;

    bf16x8 aq[2][2];
#pragma unroll
    for (int qf = 0; qf < 2; ++qf)
#pragma unroll
        for (int c = 0; c < 2; ++c)
            aq[qf][c] = *(const bf16x8*)(Qbase + (size_t)(qw + qf * 16 + l15) * 64 + c * 32 + lg * 8);

    f32x4 o[2][4] = {};
    float m0 = -1e30f, m1 = -1e30f, l0 = 0.f, l1 = 0.f;

    const int nfull = qw >> 6;           // unmasked 64-key steps
    __hip_bfloat16* Pw0 = &P_lds[wid][0][0];
    __hip_bfloat16* Pw1 = &P_lds[wid][1][0];

    // K fragment double buffer; prologue loads keys 0..63 (always in-bounds)
    bf16x8 bk[2][4][2];
#pragma unroll
    for (int kf = 0; kf < 4; ++kf) {
        const __hip_bfloat16* kp = Kbase + (size_t)(kf * 16 + l15) * 64 + lg * 8;
        bk[0][kf][0] = *(const bf16x8*)(kp);
        bk[0][kf][1] = *(const bf16x8*)(kp + 32);
    }

    for (int t = 0; t < nfull; ++t) {
        const int ks = t * 64;
        const int cur = t & 1;
        // V for this step (consumed ~end of iteration)
        bf16x8 bv[4][2];
#pragma unroll
        for (int dc = 0; dc < 4; ++dc) {
            const __hip_bfloat16* vp = Vbase + (size_t)(dc * 16 + l15) * 2048 + ks + lg * 8;
            bv[dc][0] = *(const bf16x8*)(vp);
            bv[dc][1] = *(const bf16x8*)(vp + 32);
        }
        // prefetch K for step t+1 (covers tail step too; rows <= 2047)
#pragma unroll
        for (int kf = 0; kf < 4; ++kf) {
            const __hip_bfloat16* kp = Kbase + (size_t)(ks + 64 + kf * 16 + l15) * 64 + lg * 8;
            bk[cur ^ 1][kf][0] = *(const bf16x8*)(kp);
            bk[cur ^ 1][kf][1] = *(const bf16x8*)(kp + 32);
        }
        // QK^T, both qf, dense MFMA cluster
        f32x4 s0[4] = {}, s1[4] = {};
#pragma unroll
        for (int kf = 0; kf < 4; ++kf) {
            s0[kf] = __builtin_amdgcn_mfma_f32_16x16x32_bf16(bk[cur][kf][0], aq[0][0], s0[kf], 0, 0, 0);
            s0[kf] = __builtin_amdgcn_mfma_f32_16x16x32_bf16(bk[cur][kf][1], aq[0][1], s0[kf], 0, 0, 0);
            s1[kf] = __builtin_amdgcn_mfma_f32_16x16x32_bf16(bk[cur][kf][0], aq[1][0], s1[kf], 0, 0, 0);
            s1[kf] = __builtin_amdgcn_mfma_f32_16x16x32_bf16(bk[cur][kf][1], aq[1][1], s1[kf], 0, 0, 0);
        }
        // tile max (no causal mask needed: fully unmasked step)
        float px0 = fmaxf(fmaxf(fmaxf(s0[0][0], s0[0][1]), fmaxf(s0[0][2], s0[0][3])),
                          fmaxf(fmaxf(s0[1][0], s0[1][1]), fmaxf(s0[1][2], s0[1][3])));
        px0 = fmaxf(px0, fmaxf(fmaxf(fmaxf(s0[2][0], s0[2][1]), fmaxf(s0[2][2], s0[2][3])),
                               fmaxf(fmaxf(s0[3][0], s0[3][1]), fmaxf(s0[3][2], s0[3][3]))));
        float px1 = fmaxf(fmaxf(fmaxf(s1[0][0], s1[0][1]), fmaxf(s1[0][2], s1[0][3])),
                          fmaxf(fmaxf(s1[1][0], s1[1][1]), fmaxf(s1[1][2], s1[1][3])));
        px1 = fmaxf(px1, fmaxf(fmaxf(fmaxf(s1[2][0], s1[2][1]), fmaxf(s1[2][2], s1[2][3])),
                               fmaxf(fmaxf(s1[3][0], s1[3][1]), fmaxf(s1[3][2], s1[3][3]))));
        px0 = fmaxf(px0, __shfl_xor(px0, 16));
        px0 = fmaxf(px0, __shfl_xor(px0, 32));
        px1 = fmaxf(px1, __shfl_xor(px1, 16));
        px1 = fmaxf(px1, __shfl_xor(px1, 32));
        // defer-max: rescale only if tile max exceeds running max + THR
        if (__any((px0 > m0 + DEFER_THR) || (px1 > m1 + DEFER_THR))) {
            const float mn0 = fmaxf(m0, px0), mn1 = fmaxf(m1, px1);
            const float al0 = exp2fast(m0 - mn0), al1 = exp2fast(m1 - mn1);
            m0 = mn0; m1 = mn1;
            l0 *= al0; l1 *= al1;
#pragma unroll
            for (int dc = 0; dc < 4; ++dc)
#pragma unroll
                for (int r = 0; r < 4; ++r) {
                    o[0][dc][r] *= al0;
                    o[1][dc][r] *= al1;
                }
        }
        // p = exp2(s - m), row sum, pack to LDS
        float rs0 = 0.f, rs1 = 0.f;
#pragma unroll
        for (int kf = 0; kf < 4; ++kf) {
#pragma unroll
            for (int r = 0; r < 4; ++r) {
                s0[kf][r] = exp2fast(s0[kf][r] - m0);
                s1[kf][r] = exp2fast(s1[kf][r] - m1);
                rs0 += s0[kf][r];
                rs1 += s1[kf][r];
            }
            uint2 w0, w1;
            w0.x = pack2(s0[kf][0], s0[kf][1]); w0.y = pack2(s0[kf][2], s0[kf][3]);
            w1.x = pack2(s1[kf][0], s1[kf][1]); w1.y = pack2(s1[kf][2], s1[kf][3]);
            const int off = l15 * 64 + ((kf * 16 + lg * 4) ^ swz);
            *(uint2*)&Pw0[off] = w0;
            *(uint2*)&Pw1[off] = w1;
        }
        rs0 += __shfl_xor(rs0, 16); rs0 += __shfl_xor(rs0, 32);
        rs1 += __shfl_xor(rs1, 16); rs1 += __shfl_xor(rs1, 32);
        l0 += rs0; l1 += rs1;
        // PV
#pragma unroll
        for (int c2 = 0; c2 < 2; ++c2) {
            const int off = l15 * 64 + ((c2 * 32 + lg * 8) ^ swz);
            const bf16x8 pb0 = *(const bf16x8*)&Pw0[off];
            const bf16x8 pb1 = *(const bf16x8*)&Pw1[off];
#pragma unroll
            for (int dc = 0; dc < 4; ++dc) {
                o[0][dc] = __builtin_amdgcn_mfma_f32_16x16x32_bf16(bv[dc][c2], pb0, o[0][dc], 0, 0, 0);
                o[1][dc] = __builtin_amdgcn_mfma_f32_16x16x32_bf16(bv[dc][c2], pb1, o[1][dc], 0, 0, 0);
            }
        }
    }

    // ---- diagonal tail: keys [nfull*64, qw+32), causal-masked ----
    {
        const int ks = nfull * 64;
        const int cur = nfull & 1;
        bf16x8 bv[4][2];
#pragma unroll
        for (int dc = 0; dc < 4; ++dc) {
            const __hip_bfloat16* vp = Vbase + (size_t)(dc * 16 + l15) * 2048 + ks + lg * 8;
            bv[dc][0] = *(const bf16x8*)(vp);
            bv[dc][1] = *(const bf16x8*)(vp + 32);
        }
        float mr[2] = {m0, m1}, lr[2] = {l0, l1};
#pragma unroll
        for (int qf = 0; qf < 2; ++qf) {
            const int qlo = qw + qf * 16;
            const int qv = qlo + l15;
            f32x4 s[4] = {};
#pragma unroll
            for (int kf = 0; kf < 4; ++kf) {
                if (ks + kf * 16 <= qlo + 15) {
                    s[kf] = __builtin_amdgcn_mfma_f32_16x16x32_bf16(bk[cur][kf][0], aq[qf][0], s[kf], 0, 0, 0);
                    s[kf] = __builtin_amdgcn_mfma_f32_16x16x32_bf16(bk[cur][kf][1], aq[qf][1], s[kf], 0, 0, 0);
                }
            }
            float p[4][4];
            const int kb = ks + lg * 4;
#pragma unroll
            for (int kf = 0; kf < 4; ++kf)
#pragma unroll
                for (int r = 0; r < 4; ++r)
                    p[kf][r] = (kb + kf * 16 + r <= qv) ? s[kf][r] : -1e30f;
            float mx = fmaxf(fmaxf(fmaxf(p[0][0], p[0][1]), fmaxf(p[0][2], p[0][3])),
                             fmaxf(fmaxf(p[1][0], p[1][1]), fmaxf(p[1][2], p[1][3])));
            mx = fmaxf(mx, fmaxf(fmaxf(fmaxf(p[2][0], p[2][1]), fmaxf(p[2][2], p[2][3])),
                                 fmaxf(fmaxf(p[3][0], p[3][1]), fmaxf(p[3][2], p[3][3]))));
            mx = fmaxf(mx, __shfl_xor(mx, 16));
            mx = fmaxf(mx, __shfl_xor(mx, 32));
            const float mnew = fmaxf(mr[qf], mx);
            const float al = exp2fast(mr[qf] - mnew);
            mr[qf] = mnew;
            float rs = 0.f;
#pragma unroll
            for (int kf = 0; kf < 4; ++kf)
#pragma unroll
                for (int r = 0; r < 4; ++r) {
                    p[kf][r] = exp2fast(p[kf][r] - mnew);
                    rs += p[kf][r];
                }
            rs += __shfl_xor(rs, 16);
            rs += __shfl_xor(rs, 32);
            lr[qf] = lr[qf] * al + rs;
#pragma unroll
            for (int dc = 0; dc < 4; ++dc)
#pragma unroll
                for (int r = 0; r < 4; ++r) o[qf][dc][r] *= al;
            __hip_bfloat16* Pw = (qf == 0) ? Pw0 : Pw1;
#pragma unroll
            for (int kf = 0; kf < 4; ++kf) {
                uint2 w;
                w.x = pack2(p[kf][0], p[kf][1]);
                w.y = pack2(p[kf][2], p[kf][3]);
                *(uint2*)&Pw[l15 * 64 + ((kf * 16 + lg * 4) ^ swz)] = w;
            }
#pragma unroll
            for (int c2 = 0; c2 < 2; ++c2) {
                if (ks + c2 * 32 <= qlo + 15) {
                    const bf16x8 pb = *(const bf16x8*)&Pw[l15 * 64 + ((c2 * 32 + lg * 8) ^ swz)];
#pragma unroll
                    for (int dc = 0; dc < 4; ++dc)
                        o[qf][dc] = __builtin_amdgcn_mfma_f32_16x16x32_bf16(bv[dc][c2], pb, o[qf][dc], 0, 0, 0);
                }
            }
        }
        l0 = lr[0]; l1 = lr[1];
    }

    const int bq = bh >> 4, hh = bh & 15;
    const float inv0 = 1.0f / l0, inv1 = 1.0f / l1;
#pragma unroll
    for (int qf = 0; qf < 2; ++qf) {
        const float inv = (qf == 0) ? inv0 : inv1;
        const size_t rowb = ((size_t)(bq * 2048 + qw + qf * 16 + l15)) * 1024 + hh * 64;
#pragma unroll
        for (int dc = 0; dc < 4; ++dc) {
            bf16x4 st;
#pragma unroll
            for (int r = 0; r < 4; ++r)
                st[r] = (short)__bfloat16_as_ushort(__float2bfloat16(o[qf][dc][r] * inv));
            *(bf16x4*)(att + rowb + dc * 16 + lg * 4) = st;
        }
    }
}

// ---------------------------------------------------------------------------
extern "C" void kernel_launch(void* const* d_in, const int* in_sizes, int n_in,
                              void* d_out, int out_size, void* d_ws, size_t ws_size,
                              hipStream_t stream)
{
    const float* x    = (const float*)d_in[0];   // [2,2048,1024]
    const float* Wqkv = (const float*)d_in[1];   // [1024,3072]
    const float* bqkv = (const float*)d_in[2];   // [3072]
    const float* Wo   = (const float*)d_in[3];   // [1024,1024]
    const float* bo   = (const float*)d_in[4];   // [1024]
    float* out = (float*)d_out;                  // [2,2048,1024]

    char* ws = (char*)d_ws;
    const size_t MB = 1024 * 1024;
    __hip_bfloat16* xb    = (__hip_bfloat16*)(ws);            //  8 MB
    __hip_bfloat16* WqkvT = (__hip_bfloat16*)(ws + 8 * MB);   //  6 MB
    __hip_bfloat16* WoT   = (__hip_bfloat16*)(ws + 14 * MB);  //  2 MB
    __hip_bfloat16* Qb    = (__hip_bfloat16*)(ws + 16 * MB);  //  8 MB
    __hip_bfloat16* Kb    = (__hip_bfloat16*)(ws + 24 * MB);  //  8 MB
    __hip_bfloat16* Vt    = (__hip_bfloat16*)(ws + 32 * MB);  //  8 MB
    __hip_bfloat16* att   = (__hip_bfloat16*)(ws + 40 * MB);  //  8 MB

    k_f32_to_bf16<<<2048, 256, 0, stream>>>(x, xb, 4096 * 1024 / 4);
    k_transpose_f32_bf16<<<dim3(96, 32), 256, 0, stream>>>(Wqkv, WqkvT, 1024, 3072);
    k_transpose_f32_bf16<<<dim3(32, 32), 256, 0, stream>>>(Wo, WoT, 1024, 1024);

    k_gemm_bt<0><<<dim3(24, 32), 256, 0, stream>>>(
        xb, WqkvT, bqkv, 1024, 3072, nullptr, Qb, Kb, Vt);

    k_attn<<<512, 256, 0, stream>>>(Qb, Kb, Vt, att);

    k_gemm_bt<1><<<dim3(8, 32), 256, 0, stream>>>(
        att, WoT, bo, 1024, 1024, out, nullptr, nullptr, nullptr);
}

// Round 5
// 172.020 us; speedup vs baseline: 1.5057x; 1.5057x over previous
//
#include <hip/hip_runtime.h>
#include <hip/hip_bf16.h>

typedef __attribute__((ext_vector_type(8))) short bf16x8;
typedef __attribute__((ext_vector_type(4))) short bf16x4;
typedef __attribute__((ext_vector_type(4))) float f32x4;

static __device__ __forceinline__ __hip_bfloat16 f2b(float f) {
    return __float2bfloat16(f);
}
static __device__ __forceinline__ unsigned pack2(float a, float b) {
    unsigned ua = (unsigned)__bfloat16_as_ushort(__float2bfloat16(a));
    unsigned ub = (unsigned)__bfloat16_as_ushort(__float2bfloat16(b));
    return ua | (ub << 16);
}
static __device__ __forceinline__ float exp2fast(float x) {
    return __builtin_amdgcn_exp2f(x);
}

// ---------------------------------------------------------------------------
// f32 -> bf16 elementwise convert
// ---------------------------------------------------------------------------
__global__ __launch_bounds__(256) void k_f32_to_bf16(
    const float* __restrict__ in, __hip_bfloat16* __restrict__ out, int n4)
{
    int i = blockIdx.x * blockDim.x + threadIdx.x;
    int stride = gridDim.x * blockDim.x;
    for (; i < n4; i += stride) {
        float4 v = reinterpret_cast<const float4*>(in)[i];
        __hip_bfloat16* o = out + 4 * (size_t)i;
        o[0] = f2b(v.x); o[1] = f2b(v.y); o[2] = f2b(v.z); o[3] = f2b(v.w);
    }
}

// ---------------------------------------------------------------------------
// f32 [R][Cn] -> bf16 [Cn][R] tiled transpose
// ---------------------------------------------------------------------------
__global__ __launch_bounds__(256) void k_transpose_f32_bf16(
    const float* __restrict__ in, __hip_bfloat16* __restrict__ out, int R, int Cn)
{
    __shared__ float tile[32][33];
    const int c0 = blockIdx.x * 32, r0 = blockIdx.y * 32;
    const int tx = threadIdx.x & 31, ty = threadIdx.x >> 5;
#pragma unroll
    for (int i = 0; i < 32; i += 8)
        tile[ty + i][tx] = in[(size_t)(r0 + ty + i) * Cn + c0 + tx];
    __syncthreads();
#pragma unroll
    for (int i = 0; i < 32; i += 8)
        out[(size_t)(c0 + ty + i) * R + r0 + tx] = f2b(tile[tx][ty + i]);
}

// ---------------------------------------------------------------------------
// GEMM: C[M][N] = A[M][K] @ Bt[N][K]^T + bias  (m97 structure)
// ---------------------------------------------------------------------------
#define QSCALE 0.1803368801111f   // 0.125 * log2(e)

template <int EPI>
__global__ __launch_bounds__(256) void k_gemm_bt(
    const __hip_bfloat16* __restrict__ A,
    const __hip_bfloat16* __restrict__ Bt,
    const float* __restrict__ bias,
    int K, int Nn,
    float* __restrict__ outf,
    __hip_bfloat16* __restrict__ Qb,
    __hip_bfloat16* __restrict__ Kb,
    __hip_bfloat16* __restrict__ Vt)
{
    __shared__ __hip_bfloat16 As[128][64];
    __shared__ __hip_bfloat16 Bs[128][64];

    const int tid = threadIdx.x;
    const int lane = tid & 63;
    const int wid = tid >> 6;
    const int wm = wid >> 1, wn = wid & 1;
    const int m0 = blockIdx.y * 128, n0 = blockIdx.x * 128;
    const int l15 = lane & 15, lg = lane >> 4;

    f32x4 acc[4][4] = {};

    const int srow = tid >> 3;
    const int scol = (tid & 7) * 8;

    for (int k0 = 0; k0 < K; k0 += 64) {
#pragma unroll
        for (int i = 0; i < 4; ++i) {
            int r = srow + 32 * i;
            __builtin_amdgcn_global_load_lds(
                (const __attribute__((address_space(1))) void*)(A + (size_t)(m0 + r) * K + k0 + scol),
                (__attribute__((address_space(3))) void*)(&As[r][scol]), 16, 0, 0);
        }
#pragma unroll
        for (int i = 0; i < 4; ++i) {
            int r = srow + 32 * i;
            __builtin_amdgcn_global_load_lds(
                (const __attribute__((address_space(1))) void*)(Bt + (size_t)(n0 + r) * K + k0 + scol),
                (__attribute__((address_space(3))) void*)(&Bs[r][scol]), 16, 0, 0);
        }
        __syncthreads();
#pragma unroll
        for (int c = 0; c < 2; ++c) {
            bf16x8 a[4], bb[4];
#pragma unroll
            for (int m = 0; m < 4; ++m)
                a[m] = *(const bf16x8*)&As[wm * 64 + m * 16 + l15][c * 32 + lg * 8];
#pragma unroll
            for (int n = 0; n < 4; ++n)
                bb[n] = *(const bf16x8*)&Bs[wn * 64 + n * 16 + l15][c * 32 + lg * 8];
#pragma unroll
            for (int m = 0; m < 4; ++m)
#pragma unroll
                for (int n = 0; n < 4; ++n)
                    acc[m][n] = __builtin_amdgcn_mfma_f32_16x16x32_bf16(a[m], bb[n], acc[m][n], 0, 0, 0);
        }
        __syncthreads();
    }

#pragma unroll
    for (int m = 0; m < 4; ++m) {
        const int row = m0 + wm * 64 + m * 16 + lg * 4;
#pragma unroll
        for (int n = 0; n < 4; ++n) {
            const int col = n0 + wn * 64 + n * 16 + l15;
            const float bv = bias[col];
#pragma unroll
            for (int r = 0; r < 4; ++r) {
                float val = acc[m][n][r] + bv;
                const int rr = row + r;
                if (EPI == 0) {
                    const int sec = col >> 10, cw = col & 1023;
                    const int hh = cw >> 6, d = cw & 63;
                    const int bq = rr >> 11, t = rr & 2047;
                    const int bh = bq * 16 + hh;
                    if (sec == 0)
                        Qb[((size_t)bh * 2048 + t) * 64 + d] = f2b(val * QSCALE);
                    else if (sec == 1)
                        Kb[((size_t)bh * 2048 + t) * 64 + d] = f2b(val);
                    else
                        Vt[((size_t)bh * 64 + d) * 2048 + t] = f2b(val);
                } else {
                    outf[(size_t)rr * Nn + col] = val;
                }
            }
        }
    }
}

// ---------------------------------------------------------------------------
// Causal flash attention v5 — v4 structure with STATICALLY-NAMED K double
// buffer (bkA/bkB, parity-peeled loop) so everything stays in registers.
// ---------------------------------------------------------------------------
#define DEFER_THR 4.0f

#define K_LOAD(BK, KS)                                                          \
    {                                                                           \
        _Pragma("unroll")                                                       \
        for (int kf = 0; kf < 4; ++kf) {                                        \
            const __hip_bfloat16* kp =                                          \
                Kbase + (size_t)((KS) + kf * 16 + l15) * 64 + lg * 8;           \
            BK[kf][0] = *(const bf16x8*)(kp);                                   \
            BK[kf][1] = *(const bf16x8*)(kp + 32);                              \
        }                                                                       \
    }

#define FULL_STEP(BK, BKN, KS)                                                  \
    {                                                                           \
        const int ks_ = (KS);                                                   \
        bf16x8 bv[4][2];                                                        \
        _Pragma("unroll")                                                       \
        for (int dc = 0; dc < 4; ++dc) {                                        \
            const __hip_bfloat16* vp =                                          \
                Vbase + (size_t)(dc * 16 + l15) * 2048 + ks_ + lg * 8;          \
            bv[dc][0] = *(const bf16x8*)(vp);                                   \
            bv[dc][1] = *(const bf16x8*)(vp + 32);                              \
        }                                                                       \
        K_LOAD(BKN, ks_ + 64);                                                  \
        f32x4 s0[4] = {}, s1[4] = {};                                           \
        _Pragma("unroll")                                                       \
        for (int kf = 0; kf < 4; ++kf) {                                        \
            s0[kf] = __builtin_amdgcn_mfma_f32_16x16x32_bf16(BK[kf][0], aq[0][0], s0[kf], 0, 0, 0); \
            s0[kf] = __builtin_amdgcn_mfma_f32_16x16x32_bf16(BK[kf][1], aq[0][1], s0[kf], 0, 0, 0); \
            s1[kf] = __builtin_amdgcn_mfma_f32_16x16x32_bf16(BK[kf][0], aq[1][0], s1[kf], 0, 0, 0); \
            s1[kf] = __builtin_amdgcn_mfma_f32_16x16x32_bf16(BK[kf][1], aq[1][1], s1[kf], 0, 0, 0); \
        }                                                                       \
        float px0 = fmaxf(fmaxf(fmaxf(s0[0][0], s0[0][1]), fmaxf(s0[0][2], s0[0][3])), \
                          fmaxf(fmaxf(s0[1][0], s0[1][1]), fmaxf(s0[1][2], s0[1][3]))); \
        px0 = fmaxf(px0, fmaxf(fmaxf(fmaxf(s0[2][0], s0[2][1]), fmaxf(s0[2][2], s0[2][3])), \
                               fmaxf(fmaxf(s0[3][0], s0[3][1]), fmaxf(s0[3][2], s0[3][3])))); \
        float px1 = fmaxf(fmaxf(fmaxf(s1[0][0], s1[0][1]), fmaxf(s1[0][2], s1[0][3])), \
                          fmaxf(fmaxf(s1[1][0], s1[1][1]), fmaxf(s1[1][2], s1[1][3]))); \
        px1 = fmaxf(px1, fmaxf(fmaxf(fmaxf(s1[2][0], s1[2][1]), fmaxf(s1[2][2], s1[2][3])), \
                               fmaxf(fmaxf(s1[3][0], s1[3][1]), fmaxf(s1[3][2], s1[3][3])))); \
        px0 = fmaxf(px0, __shfl_xor(px0, 16));                                  \
        px0 = fmaxf(px0, __shfl_xor(px0, 32));                                  \
        px1 = fmaxf(px1, __shfl_xor(px1, 16));                                  \
        px1 = fmaxf(px1, __shfl_xor(px1, 32));                                  \
        if (__any((px0 > m0 + DEFER_THR) || (px1 > m1 + DEFER_THR))) {          \
            const float mn0 = fmaxf(m0, px0), mn1 = fmaxf(m1, px1);             \
            const float al0 = exp2fast(m0 - mn0), al1 = exp2fast(m1 - mn1);     \
            m0 = mn0; m1 = mn1;                                                 \
            l0 *= al0; l1 *= al1;                                               \
            _Pragma("unroll")                                                   \
            for (int dc = 0; dc < 4; ++dc)                                      \
                _Pragma("unroll")                                               \
                for (int r = 0; r < 4; ++r) {                                   \
                    o[0][dc][r] *= al0;                                         \
                    o[1][dc][r] *= al1;                                         \
                }                                                               \
        }                                                                       \
        float rs0 = 0.f, rs1 = 0.f;                                             \
        _Pragma("unroll")                                                       \
        for (int kf = 0; kf < 4; ++kf) {                                        \
            _Pragma("unroll")                                                   \
            for (int r = 0; r < 4; ++r) {                                       \
                s0[kf][r] = exp2fast(s0[kf][r] - m0);                           \
                s1[kf][r] = exp2fast(s1[kf][r] - m1);                           \
                rs0 += s0[kf][r];                                               \
                rs1 += s1[kf][r];                                               \
            }                                                                   \
            uint2 w0, w1;                                                       \
            w0.x = pack2(s0[kf][0], s0[kf][1]); w0.y = pack2(s0[kf][2], s0[kf][3]); \
            w1.x = pack2(s1[kf][0], s1[kf][1]); w1.y = pack2(s1[kf][2], s1[kf][3]); \
            const int off = l15 * 64 + ((kf * 16 + lg * 4) ^ swz);              \
            *(uint2*)&Pw0[off] = w0;                                            \
            *(uint2*)&Pw1[off] = w1;                                            \
        }                                                                       \
        rs0 += __shfl_xor(rs0, 16); rs0 += __shfl_xor(rs0, 32);                 \
        rs1 += __shfl_xor(rs1, 16); rs1 += __shfl_xor(rs1, 32);                 \
        l0 += rs0; l1 += rs1;                                                   \
        _Pragma("unroll")                                                       \
        for (int c2 = 0; c2 < 2; ++c2) {                                        \
            const int off = l15 * 64 + ((c2 * 32 + lg * 8) ^ swz);              \
            const bf16x8 pb0 = *(const bf16x8*)&Pw0[off];                       \
            const bf16x8 pb1 = *(const bf16x8*)&Pw1[off];                       \
            _Pragma("unroll")                                                   \
            for (int dc = 0; dc < 4; ++dc) {                                    \
                o[0][dc] = __builtin_amdgcn_mfma_f32_16x16x32_bf16(bv[dc][c2], pb0, o[0][dc], 0, 0, 0); \
                o[1][dc] = __builtin_amdgcn_mfma_f32_16x16x32_bf16(bv[dc][c2], pb1, o[1][dc], 0, 0, 0); \
            }                                                                   \
        }                                                                       \
    }

#define TAIL_STEP(BK)                                                           \
    {                                                                           \
        const int ks_ = nfull * 64;                                             \
        bf16x8 bv[4][2];                                                        \
        _Pragma("unroll")                                                       \
        for (int dc = 0; dc < 4; ++dc) {                                        \
            const __hip_bfloat16* vp =                                          \
                Vbase + (size_t)(dc * 16 + l15) * 2048 + ks_ + lg * 8;          \
            bv[dc][0] = *(const bf16x8*)(vp);                                   \
            bv[dc][1] = *(const bf16x8*)(vp + 32);                              \
        }                                                                       \
        float mr[2] = {m0, m1}, lr[2] = {l0, l1};                               \
        _Pragma("unroll")                                                       \
        for (int qf = 0; qf < 2; ++qf) {                                        \
            const int qlo = qw + qf * 16;                                       \
            const int qv = qlo + l15;                                           \
            f32x4 s[4] = {};                                                    \
            _Pragma("unroll")                                                   \
            for (int kf = 0; kf < 4; ++kf) {                                    \
                if (ks_ + kf * 16 <= qlo + 15) {                                \
                    s[kf] = __builtin_amdgcn_mfma_f32_16x16x32_bf16(BK[kf][0], aq[qf][0], s[kf], 0, 0, 0); \
                    s[kf] = __builtin_amdgcn_mfma_f32_16x16x32_bf16(BK[kf][1], aq[qf][1], s[kf], 0, 0, 0); \
                }                                                               \
            }                                                                   \
            float p[4][4];                                                      \
            const int kb = ks_ + lg * 4;                                        \
            _Pragma("unroll")                                                   \
            for (int kf = 0; kf < 4; ++kf)                                      \
                _Pragma("unroll")                                               \
                for (int r = 0; r < 4; ++r)                                     \
                    p[kf][r] = (kb + kf * 16 + r <= qv) ? s[kf][r] : -1e30f;    \
            float mx = fmaxf(fmaxf(fmaxf(p[0][0], p[0][1]), fmaxf(p[0][2], p[0][3])), \
                             fmaxf(fmaxf(p[1][0], p[1][1]), fmaxf(p[1][2], p[1][3]))); \
            mx = fmaxf(mx, fmaxf(fmaxf(fmaxf(p[2][0], p[2][1]), fmaxf(p[2][2], p[2][3])), \
                                 fmaxf(fmaxf(p[3][0], p[3][1]), fmaxf(p[3][2], p[3][3])))); \
            mx = fmaxf(mx, __shfl_xor(mx, 16));                                 \
            mx = fmaxf(mx, __shfl_xor(mx, 32));                                 \
            const float mnew = fmaxf(mr[qf], mx);                               \
            const float al = exp2fast(mr[qf] - mnew);                           \
            mr[qf] = mnew;                                                      \
            float rs = 0.f;                                                     \
            _Pragma("unroll")                                                   \
            for (int kf = 0; kf < 4; ++kf)                                      \
                _Pragma("unroll")                                               \
                for (int r = 0; r < 4; ++r) {                                   \
                    p[kf][r] = exp2fast(p[kf][r] - mnew);                       \
                    rs += p[kf][r];                                             \
                }                                                               \
            rs += __shfl_xor(rs, 16);                                           \
            rs += __shfl_xor(rs, 32);                                           \
            lr[qf] = lr[qf] * al + rs;                                          \
            _Pragma("unroll")                                                   \
            for (int dc = 0; dc < 4; ++dc)                                      \
                _Pragma("unroll")                                               \
                for (int r = 0; r < 4; ++r) o[qf][dc][r] *= al;                 \
            __hip_bfloat16* Pw = (qf == 0) ? Pw0 : Pw1;                         \
            _Pragma("unroll")                                                   \
            for (int kf = 0; kf < 4; ++kf) {                                    \
                uint2 w;                                                        \
                w.x = pack2(p[kf][0], p[kf][1]);                                \
                w.y = pack2(p[kf][2], p[kf][3]);                                \
                *(uint2*)&Pw[l15 * 64 + ((kf * 16 + lg * 4) ^ swz)] = w;        \
            }                                                                   \
            _Pragma("unroll")                                                   \
            for (int c2 = 0; c2 < 2; ++c2) {                                    \
                if (ks_ + c2 * 32 <= qlo + 15) {                                \
                    const bf16x8 pb = *(const bf16x8*)&Pw[l15 * 64 + ((c2 * 32 + lg * 8) ^ swz)]; \
                    _Pragma("unroll")                                           \
                    for (int dc = 0; dc < 4; ++dc)                              \
                        o[qf][dc] = __builtin_amdgcn_mfma_f32_16x16x32_bf16(bv[dc][c2], pb, o[qf][dc], 0, 0, 0); \
                }                                                               \
            }                                                                   \
        }                                                                       \
        l0 = lr[0]; l1 = lr[1];                                                 \
    }

__global__ __launch_bounds__(256, 2) void k_attn(
    const __hip_bfloat16* __restrict__ Qb,
    const __hip_bfloat16* __restrict__ Kb,
    const __hip_bfloat16* __restrict__ Vt,
    __hip_bfloat16* __restrict__ att)
{
    __shared__ __hip_bfloat16 P_lds[4][2][16 * 64];
    const int tid = threadIdx.x, lane = tid & 63, wid = tid >> 6;
    const int lid = blockIdx.x;
    const int xcd = lid & 7, j = lid >> 3;
    const int jj = j >> 2;
    const int tile = (jj < 8) ? (15 - jj) : (jj - 8);   // heavy tiles first
    const int bh = xcd * 4 + (j & 3);
    const int q0 = tile * 128;
    const int qw = q0 + wid * 32;
    const int l15 = lane & 15, lg = lane >> 4;
    const int swz = (l15 & 7) << 3;

    const __hip_bfloat16* Qbase = Qb + (size_t)bh * 2048 * 64;
    const __hip_bfloat16* Kbase = Kb + (size_t)bh * 2048 * 64;
    const __hip_bfloat16* Vbase = Vt + (size_t)bh * 64 * 2048;

    bf16x8 aq[2][2];
#pragma unroll
    for (int qf = 0; qf < 2; ++qf)
#pragma unroll
        for (int c = 0; c < 2; ++c)
            aq[qf][c] = *(const bf16x8*)(Qbase + (size_t)(qw + qf * 16 + l15) * 64 + c * 32 + lg * 8);

    f32x4 o[2][4] = {};
    float m0 = -1e30f, m1 = -1e30f, l0 = 0.f, l1 = 0.f;

    const int nfull = qw >> 6;
    __hip_bfloat16* Pw0 = &P_lds[wid][0][0];
    __hip_bfloat16* Pw1 = &P_lds[wid][1][0];

    bf16x8 bkA[4][2], bkB[4][2];
    K_LOAD(bkA, 0);

    if (nfull & 1) {
        FULL_STEP(bkA, bkB, 0);
        for (int t = 1; t < nfull; t += 2) {
            FULL_STEP(bkB, bkA, t * 64);
            FULL_STEP(bkA, bkB, (t + 1) * 64);
        }
        TAIL_STEP(bkB);
    } else {
        for (int t = 0; t < nfull; t += 2) {
            FULL_STEP(bkA, bkB, t * 64);
            FULL_STEP(bkB, bkA, (t + 1) * 64);
        }
        TAIL_STEP(bkA);
    }

    const int bq = bh >> 4, hh = bh & 15;
    const float inv0 = 1.0f / l0, inv1 = 1.0f / l1;
#pragma unroll
    for (int qf = 0; qf < 2; ++qf) {
        const float inv = (qf == 0) ? inv0 : inv1;
        const size_t rowb = ((size_t)(bq * 2048 + qw + qf * 16 + l15)) * 1024 + hh * 64;
#pragma unroll
        for (int dc = 0; dc < 4; ++dc) {
            bf16x4 st;
#pragma unroll
            for (int r = 0; r < 4; ++r)
                st[r] = (short)__bfloat16_as_ushort(__float2bfloat16(o[qf][dc][r] * inv));
            *(bf16x4*)(att + rowb + dc * 16 + lg * 4) = st;
        }
    }
}

// ---------------------------------------------------------------------------
extern "C" void kernel_launch(void* const* d_in, const int* in_sizes, int n_in,
                              void* d_out, int out_size, void* d_ws, size_t ws_size,
                              hipStream_t stream)
{
    const float* x    = (const float*)d_in[0];   // [2,2048,1024]
    const float* Wqkv = (const float*)d_in[1];   // [1024,3072]
    const float* bqkv = (const float*)d_in[2];   // [3072]
    const float* Wo   = (const float*)d_in[3];   // [1024,1024]
    const float* bo   = (const float*)d_in[4];   // [1024]
    float* out = (float*)d_out;                  // [2,2048,1024]

    char* ws = (char*)d_ws;
    const size_t MB = 1024 * 1024;
    __hip_bfloat16* xb    = (__hip_bfloat16*)(ws);            //  8 MB
    __hip_bfloat16* WqkvT = (__hip_bfloat16*)(ws + 8 * MB);   //  6 MB
    __hip_bfloat16* WoT   = (__hip_bfloat16*)(ws + 14 * MB);  //  2 MB
    __hip_bfloat16* Qb    = (__hip_bfloat16*)(ws + 16 * MB);  //  8 MB
    __hip_bfloat16* Kb    = (__hip_bfloat16*)(ws + 24 * MB);  //  8 MB
    __hip_bfloat16* Vt    = (__hip_bfloat16*)(ws + 32 * MB);  //  8 MB
    __hip_bfloat16* att   = (__hip_bfloat16*)(ws + 40 * MB);  //  8 MB

    k_f32_to_bf16<<<2048, 256, 0, stream>>>(x, xb, 4096 * 1024 / 4);
    k_transpose_f32_bf16<<<dim3(96, 32), 256, 0, stream>>>(Wqkv, WqkvT, 1024, 3072);
    k_transpose_f32_bf16<<<dim3(32, 32), 256, 0, stream>>>(Wo, WoT, 1024, 1024);

    k_gemm_bt<0><<<dim3(24, 32), 256, 0, stream>>>(
        xb, WqkvT, bqkv, 1024, 3072, nullptr, Qb, Kb, Vt);

    k_attn<<<512, 256, 0, stream>>>(Qb, Kb, Vt, att);

    k_gemm_bt<1><<<dim3(8, 32), 256, 0, stream>>>(
        att, WoT, bo, 1024, 1024, out, nullptr, nullptr, nullptr);
}

// Round 6
// 167.605 us; speedup vs baseline: 1.5453x; 1.0263x over previous
//
#include <hip/hip_runtime.h>
#include <hip/hip_bf16.h>

typedef __attribute__((ext_vector_type(8))) short bf16x8;
typedef __attribute__((ext_vector_type(4))) short bf16x4;
typedef __attribute__((ext_vector_type(4))) float f32x4;

static __device__ __forceinline__ __hip_bfloat16 f2b(float f) {
    return __float2bfloat16(f);
}
static __device__ __forceinline__ unsigned pack2(float a, float b) {
    unsigned ua = (unsigned)__bfloat16_as_ushort(__float2bfloat16(a));
    unsigned ub = (unsigned)__bfloat16_as_ushort(__float2bfloat16(b));
    return ua | (ub << 16);
}
static __device__ __forceinline__ float exp2fast(float x) {
    return __builtin_amdgcn_exp2f(x);
}

// ---------------------------------------------------------------------------
// f32 -> bf16 elementwise convert
// ---------------------------------------------------------------------------
__global__ __launch_bounds__(256) void k_f32_to_bf16(
    const float* __restrict__ in, __hip_bfloat16* __restrict__ out, int n4)
{
    int i = blockIdx.x * blockDim.x + threadIdx.x;
    int stride = gridDim.x * blockDim.x;
    for (; i < n4; i += stride) {
        float4 v = reinterpret_cast<const float4*>(in)[i];
        __hip_bfloat16* o = out + 4 * (size_t)i;
        o[0] = f2b(v.x); o[1] = f2b(v.y); o[2] = f2b(v.z); o[3] = f2b(v.w);
    }
}

// ---------------------------------------------------------------------------
// f32 [R][Cn] -> bf16 [Cn][R] tiled transpose
// ---------------------------------------------------------------------------
__global__ __launch_bounds__(256) void k_transpose_f32_bf16(
    const float* __restrict__ in, __hip_bfloat16* __restrict__ out, int R, int Cn)
{
    __shared__ float tile[32][33];
    const int c0 = blockIdx.x * 32, r0 = blockIdx.y * 32;
    const int tx = threadIdx.x & 31, ty = threadIdx.x >> 5;
#pragma unroll
    for (int i = 0; i < 32; i += 8)
        tile[ty + i][tx] = in[(size_t)(r0 + ty + i) * Cn + c0 + tx];
    __syncthreads();
#pragma unroll
    for (int i = 0; i < 32; i += 8)
        out[(size_t)(c0 + ty + i) * R + r0 + tx] = f2b(tile[tx][ty + i]);
}

// ---------------------------------------------------------------------------
// GEMM: C[M][N] = A[M][K] @ Bt[N][K]^T + bias
// v2: 2-phase double-buffered LDS (T3 minimal recipe): issue next K-tile's
// global_load_lds BEFORE current tile's compute; one vmcnt(0)+barrier per
// iteration (emitted by __syncthreads). setprio(1) around MFMA cluster.
// ---------------------------------------------------------------------------
#define QSCALE 0.1803368801111f   // 0.125 * log2(e)

#define GSTAGE(buf, k0base)                                                     \
    {                                                                           \
        _Pragma("unroll")                                                       \
        for (int i = 0; i < 4; ++i) {                                           \
            int r = srow + 32 * i;                                              \
            __builtin_amdgcn_global_load_lds(                                   \
                (const __attribute__((address_space(1))) void*)(A + (size_t)(m0 + r) * K + (k0base) + scol), \
                (__attribute__((address_space(3))) void*)(&As[buf][r][scol]), 16, 0, 0); \
        }                                                                       \
        _Pragma("unroll")                                                       \
        for (int i = 0; i < 4; ++i) {                                           \
            int r = srow + 32 * i;                                              \
            __builtin_amdgcn_global_load_lds(                                   \
                (const __attribute__((address_space(1))) void*)(Bt + (size_t)(n0 + r) * K + (k0base) + scol), \
                (__attribute__((address_space(3))) void*)(&Bs[buf][r][scol]), 16, 0, 0); \
        }                                                                       \
    }

template <int EPI>
__global__ __launch_bounds__(256) void k_gemm_bt(
    const __hip_bfloat16* __restrict__ A,
    const __hip_bfloat16* __restrict__ Bt,
    const float* __restrict__ bias,
    int K, int Nn,
    float* __restrict__ outf,
    __hip_bfloat16* __restrict__ Qb,
    __hip_bfloat16* __restrict__ Kb,
    __hip_bfloat16* __restrict__ Vt)
{
    __shared__ __hip_bfloat16 As[2][128][64];
    __shared__ __hip_bfloat16 Bs[2][128][64];

    const int tid = threadIdx.x;
    const int lane = tid & 63;
    const int wid = tid >> 6;
    const int wm = wid >> 1, wn = wid & 1;
    const int m0 = blockIdx.y * 128, n0 = blockIdx.x * 128;
    const int l15 = lane & 15, lg = lane >> 4;

    f32x4 acc[4][4] = {};

    const int srow = tid >> 3;
    const int scol = (tid & 7) * 8;
    const int nt = K >> 6;

    GSTAGE(0, 0);
    __syncthreads();                 // vmcnt(0) drain + barrier
    int cur = 0;
    for (int t = 0; t < nt; ++t) {
        if (t + 1 < nt) GSTAGE(cur ^ 1, (t + 1) << 6);   // prefetch in flight
#pragma unroll
        for (int c = 0; c < 2; ++c) {
            bf16x8 a[4], bb[4];
#pragma unroll
            for (int m = 0; m < 4; ++m)
                a[m] = *(const bf16x8*)&As[cur][wm * 64 + m * 16 + l15][c * 32 + lg * 8];
#pragma unroll
            for (int n = 0; n < 4; ++n)
                bb[n] = *(const bf16x8*)&Bs[cur][wn * 64 + n * 16 + l15][c * 32 + lg * 8];
            __builtin_amdgcn_s_setprio(1);
#pragma unroll
            for (int m = 0; m < 4; ++m)
#pragma unroll
                for (int n = 0; n < 4; ++n)
                    acc[m][n] = __builtin_amdgcn_mfma_f32_16x16x32_bf16(a[m], bb[n], acc[m][n], 0, 0, 0);
            __builtin_amdgcn_s_setprio(0);
        }
        __syncthreads();             // drains staged loads + protects reuse
        cur ^= 1;
    }

#pragma unroll
    for (int m = 0; m < 4; ++m) {
        const int row = m0 + wm * 64 + m * 16 + lg * 4;
#pragma unroll
        for (int n = 0; n < 4; ++n) {
            const int col = n0 + wn * 64 + n * 16 + l15;
            const float bv = bias[col];
#pragma unroll
            for (int r = 0; r < 4; ++r) {
                float val = acc[m][n][r] + bv;
                const int rr = row + r;
                if (EPI == 0) {
                    const int sec = col >> 10, cw = col & 1023;
                    const int hh = cw >> 6, d = cw & 63;
                    const int bq = rr >> 11, t = rr & 2047;
                    const int bh = bq * 16 + hh;
                    if (sec == 0)
                        Qb[((size_t)bh * 2048 + t) * 64 + d] = f2b(val * QSCALE);
                    else if (sec == 1)
                        Kb[((size_t)bh * 2048 + t) * 64 + d] = f2b(val);
                    else
                        Vt[((size_t)bh * 64 + d) * 2048 + t] = f2b(val);
                } else {
                    outf[(size_t)rr * Nn + col] = val;
                }
            }
        }
    }
}

// ---------------------------------------------------------------------------
// Causal flash attention v5 (statically-named K double buffer) + setprio
// around MFMA clusters.
// ---------------------------------------------------------------------------
#define DEFER_THR 4.0f

#define K_LOAD(BK, KS)                                                          \
    {                                                                           \
        _Pragma("unroll")                                                       \
        for (int kf = 0; kf < 4; ++kf) {                                        \
            const __hip_bfloat16* kp =                                          \
                Kbase + (size_t)((KS) + kf * 16 + l15) * 64 + lg * 8;           \
            BK[kf][0] = *(const bf16x8*)(kp);                                   \
            BK[kf][1] = *(const bf16x8*)(kp + 32);                              \
        }                                                                       \
    }

#define FULL_STEP(BK, BKN, KS)                                                  \
    {                                                                           \
        const int ks_ = (KS);                                                   \
        bf16x8 bv[4][2];                                                        \
        _Pragma("unroll")                                                       \
        for (int dc = 0; dc < 4; ++dc) {                                        \
            const __hip_bfloat16* vp =                                          \
                Vbase + (size_t)(dc * 16 + l15) * 2048 + ks_ + lg * 8;          \
            bv[dc][0] = *(const bf16x8*)(vp);                                   \
            bv[dc][1] = *(const bf16x8*)(vp + 32);                              \
        }                                                                       \
        K_LOAD(BKN, ks_ + 64);                                                  \
        f32x4 s0[4] = {}, s1[4] = {};                                           \
        __builtin_amdgcn_s_setprio(1);                                          \
        _Pragma("unroll")                                                       \
        for (int kf = 0; kf < 4; ++kf) {                                        \
            s0[kf] = __builtin_amdgcn_mfma_f32_16x16x32_bf16(BK[kf][0], aq[0][0], s0[kf], 0, 0, 0); \
            s0[kf] = __builtin_amdgcn_mfma_f32_16x16x32_bf16(BK[kf][1], aq[0][1], s0[kf], 0, 0, 0); \
            s1[kf] = __builtin_amdgcn_mfma_f32_16x16x32_bf16(BK[kf][0], aq[1][0], s1[kf], 0, 0, 0); \
            s1[kf] = __builtin_amdgcn_mfma_f32_16x16x32_bf16(BK[kf][1], aq[1][1], s1[kf], 0, 0, 0); \
        }                                                                       \
        __builtin_amdgcn_s_setprio(0);                                          \
        float px0 = fmaxf(fmaxf(fmaxf(s0[0][0], s0[0][1]), fmaxf(s0[0][2], s0[0][3])), \
                          fmaxf(fmaxf(s0[1][0], s0[1][1]), fmaxf(s0[1][2], s0[1][3]))); \
        px0 = fmaxf(px0, fmaxf(fmaxf(fmaxf(s0[2][0], s0[2][1]), fmaxf(s0[2][2], s0[2][3])), \
                               fmaxf(fmaxf(s0[3][0], s0[3][1]), fmaxf(s0[3][2], s0[3][3])))); \
        float px1 = fmaxf(fmaxf(fmaxf(s1[0][0], s1[0][1]), fmaxf(s1[0][2], s1[0][3])), \
                          fmaxf(fmaxf(s1[1][0], s1[1][1]), fmaxf(s1[1][2], s1[1][3]))); \
        px1 = fmaxf(px1, fmaxf(fmaxf(fmaxf(s1[2][0], s1[2][1]), fmaxf(s1[2][2], s1[2][3])), \
                               fmaxf(fmaxf(s1[3][0], s1[3][1]), fmaxf(s1[3][2], s1[3][3])))); \
        px0 = fmaxf(px0, __shfl_xor(px0, 16));                                  \
        px0 = fmaxf(px0, __shfl_xor(px0, 32));                                  \
        px1 = fmaxf(px1, __shfl_xor(px1, 16));                                  \
        px1 = fmaxf(px1, __shfl_xor(px1, 32));                                  \
        if (__any((px0 > m0 + DEFER_THR) || (px1 > m1 + DEFER_THR))) {          \
            const float mn0 = fmaxf(m0, px0), mn1 = fmaxf(m1, px1);             \
            const float al0 = exp2fast(m0 - mn0), al1 = exp2fast(m1 - mn1);     \
            m0 = mn0; m1 = mn1;                                                 \
            l0 *= al0; l1 *= al1;                                               \
            _Pragma("unroll")                                                   \
            for (int dc = 0; dc < 4; ++dc)                                      \
                _Pragma("unroll")                                               \
                for (int r = 0; r < 4; ++r) {                                   \
                    o[0][dc][r] *= al0;                                         \
                    o[1][dc][r] *= al1;                                         \
                }                                                               \
        }                                                                       \
        float rs0 = 0.f, rs1 = 0.f;                                             \
        _Pragma("unroll")                                                       \
        for (int kf = 0; kf < 4; ++kf) {                                        \
            _Pragma("unroll")                                                   \
            for (int r = 0; r < 4; ++r) {                                       \
                s0[kf][r] = exp2fast(s0[kf][r] - m0);                           \
                s1[kf][r] = exp2fast(s1[kf][r] - m1);                           \
                rs0 += s0[kf][r];                                               \
                rs1 += s1[kf][r];                                               \
            }                                                                   \
            uint2 w0, w1;                                                       \
            w0.x = pack2(s0[kf][0], s0[kf][1]); w0.y = pack2(s0[kf][2], s0[kf][3]); \
            w1.x = pack2(s1[kf][0], s1[kf][1]); w1.y = pack2(s1[kf][2], s1[kf][3]); \
            const int off = l15 * 64 + ((kf * 16 + lg * 4) ^ swz);              \
            *(uint2*)&Pw0[off] = w0;                                            \
            *(uint2*)&Pw1[off] = w1;                                            \
        }                                                                       \
        rs0 += __shfl_xor(rs0, 16); rs0 += __shfl_xor(rs0, 32);                 \
        rs1 += __shfl_xor(rs1, 16); rs1 += __shfl_xor(rs1, 32);                 \
        l0 += rs0; l1 += rs1;                                                   \
        _Pragma("unroll")                                                       \
        for (int c2 = 0; c2 < 2; ++c2) {                                        \
            const int off = l15 * 64 + ((c2 * 32 + lg * 8) ^ swz);              \
            const bf16x8 pb0 = *(const bf16x8*)&Pw0[off];                       \
            const bf16x8 pb1 = *(const bf16x8*)&Pw1[off];                       \
            __builtin_amdgcn_s_setprio(1);                                      \
            _Pragma("unroll")                                                   \
            for (int dc = 0; dc < 4; ++dc) {                                    \
                o[0][dc] = __builtin_amdgcn_mfma_f32_16x16x32_bf16(bv[dc][c2], pb0, o[0][dc], 0, 0, 0); \
                o[1][dc] = __builtin_amdgcn_mfma_f32_16x16x32_bf16(bv[dc][c2], pb1, o[1][dc], 0, 0, 0); \
            }                                                                   \
            __builtin_amdgcn_s_setprio(0);                                      \
        }                                                                       \
    }

#define TAIL_STEP(BK)                                                           \
    {                                                                           \
        const int ks_ = nfull * 64;                                             \
        bf16x8 bv[4][2];                                                        \
        _Pragma("unroll")                                                       \
        for (int dc = 0; dc < 4; ++dc) {                                        \
            const __hip_bfloat16* vp =                                          \
                Vbase + (size_t)(dc * 16 + l15) * 2048 + ks_ + lg * 8;          \
            bv[dc][0] = *(const bf16x8*)(vp);                                   \
            bv[dc][1] = *(const bf16x8*)(vp + 32);                              \
        }                                                                       \
        float mr[2] = {m0, m1}, lr[2] = {l0, l1};                               \
        _Pragma("unroll")                                                       \
        for (int qf = 0; qf < 2; ++qf) {                                        \
            const int qlo = qw + qf * 16;                                       \
            const int qv = qlo + l15;                                           \
            f32x4 s[4] = {};                                                    \
            _Pragma("unroll")                                                   \
            for (int kf = 0; kf < 4; ++kf) {                                    \
                if (ks_ + kf * 16 <= qlo + 15) {                                \
                    s[kf] = __builtin_amdgcn_mfma_f32_16x16x32_bf16(BK[kf][0], aq[qf][0], s[kf], 0, 0, 0); \
                    s[kf] = __builtin_amdgcn_mfma_f32_16x16x32_bf16(BK[kf][1], aq[qf][1], s[kf], 0, 0, 0); \
                }                                                               \
            }                                                                   \
            float p[4][4];                                                      \
            const int kb = ks_ + lg * 4;                                        \
            _Pragma("unroll")                                                   \
            for (int kf = 0; kf < 4; ++kf)                                      \
                _Pragma("unroll")                                               \
                for (int r = 0; r < 4; ++r)                                     \
                    p[kf][r] = (kb + kf * 16 + r <= qv) ? s[kf][r] : -1e30f;    \
            float mx = fmaxf(fmaxf(fmaxf(p[0][0], p[0][1]), fmaxf(p[0][2], p[0][3])), \
                             fmaxf(fmaxf(p[1][0], p[1][1]), fmaxf(p[1][2], p[1][3]))); \
            mx = fmaxf(mx, fmaxf(fmaxf(fmaxf(p[2][0], p[2][1]), fmaxf(p[2][2], p[2][3])), \
                                 fmaxf(fmaxf(p[3][0], p[3][1]), fmaxf(p[3][2], p[3][3])))); \
            mx = fmaxf(mx, __shfl_xor(mx, 16));                                 \
            mx = fmaxf(mx, __shfl_xor(mx, 32));                                 \
            const float mnew = fmaxf(mr[qf], mx);                               \
            const float al = exp2fast(mr[qf] - mnew);                           \
            mr[qf] = mnew;                                                      \
            float rs = 0.f;                                                     \
            _Pragma("unroll")                                                   \
            for (int kf = 0; kf < 4; ++kf)                                      \
                _Pragma("unroll")                                               \
                for (int r = 0; r < 4; ++r) {                                   \
                    p[kf][r] = exp2fast(p[kf][r] - mnew);                       \
                    rs += p[kf][r];                                             \
                }                                                               \
            rs += __shfl_xor(rs, 16);                                           \
            rs += __shfl_xor(rs, 32);                                           \
            lr[qf] = lr[qf] * al + rs;                                          \
            _Pragma("unroll")                                                   \
            for (int dc = 0; dc < 4; ++dc)                                      \
                _Pragma("unroll")                                               \
                for (int r = 0; r < 4; ++r) o[qf][dc][r] *= al;                 \
            __hip_bfloat16* Pw = (qf == 0) ? Pw0 : Pw1;                         \
            _Pragma("unroll")                                                   \
            for (int kf = 0; kf < 4; ++kf) {                                    \
                uint2 w;                                                        \
                w.x = pack2(p[kf][0], p[kf][1]);                                \
                w.y = pack2(p[kf][2], p[kf][3]);                                \
                *(uint2*)&Pw[l15 * 64 + ((kf * 16 + lg * 4) ^ swz)] = w;        \
            }                                                                   \
            _Pragma("unroll")                                                   \
            for (int c2 = 0; c2 < 2; ++c2) {                                    \
                if (ks_ + c2 * 32 <= qlo + 15) {                                \
                    const bf16x8 pb = *(const bf16x8*)&Pw[l15 * 64 + ((c2 * 32 + lg * 8) ^ swz)]; \
                    _Pragma("unroll")                                           \
                    for (int dc = 0; dc < 4; ++dc)                              \
                        o[qf][dc] = __builtin_amdgcn_mfma_f32_16x16x32_bf16(bv[dc][c2], pb, o[qf][dc], 0, 0, 0); \
                }                                                               \
            }                                                                   \
        }                                                                       \
        l0 = lr[0]; l1 = lr[1];                                                 \
    }

__global__ __launch_bounds__(256, 2) void k_attn(
    const __hip_bfloat16* __restrict__ Qb,
    const __hip_bfloat16* __restrict__ Kb,
    const __hip_bfloat16* __restrict__ Vt,
    __hip_bfloat16* __restrict__ att)
{
    __shared__ __hip_bfloat16 P_lds[4][2][16 * 64];
    const int tid = threadIdx.x, lane = tid & 63, wid = tid >> 6;
    const int lid = blockIdx.x;
    const int xcd = lid & 7, j = lid >> 3;
    const int jj = j >> 2;
    const int tile = (jj < 8) ? (15 - jj) : (jj - 8);   // heavy tiles first
    const int bh = xcd * 4 + (j & 3);
    const int q0 = tile * 128;
    const int qw = q0 + wid * 32;
    const int l15 = lane & 15, lg = lane >> 4;
    const int swz = (l15 & 7) << 3;

    const __hip_bfloat16* Qbase = Qb + (size_t)bh * 2048 * 64;
    const __hip_bfloat16* Kbase = Kb + (size_t)bh * 2048 * 64;
    const __hip_bfloat16* Vbase = Vt + (size_t)bh * 64 * 2048;

    bf16x8 aq[2][2];
#pragma unroll
    for (int qf = 0; qf < 2; ++qf)
#pragma unroll
        for (int c = 0; c < 2; ++c)
            aq[qf][c] = *(const bf16x8*)(Qbase + (size_t)(qw + qf * 16 + l15) * 64 + c * 32 + lg * 8);

    f32x4 o[2][4] = {};
    float m0 = -1e30f, m1 = -1e30f, l0 = 0.f, l1 = 0.f;

    const int nfull = qw >> 6;
    __hip_bfloat16* Pw0 = &P_lds[wid][0][0];
    __hip_bfloat16* Pw1 = &P_lds[wid][1][0];

    bf16x8 bkA[4][2], bkB[4][2];
    K_LOAD(bkA, 0);

    if (nfull & 1) {
        FULL_STEP(bkA, bkB, 0);
        for (int t = 1; t < nfull; t += 2) {
            FULL_STEP(bkB, bkA, t * 64);
            FULL_STEP(bkA, bkB, (t + 1) * 64);
        }
        TAIL_STEP(bkB);
    } else {
        for (int t = 0; t < nfull; t += 2) {
            FULL_STEP(bkA, bkB, t * 64);
            FULL_STEP(bkB, bkA, (t + 1) * 64);
        }
        TAIL_STEP(bkA);
    }

    const int bq = bh >> 4, hh = bh & 15;
    const float inv0 = 1.0f / l0, inv1 = 1.0f / l1;
#pragma unroll
    for (int qf = 0; qf < 2; ++qf) {
        const float inv = (qf == 0) ? inv0 : inv1;
        const size_t rowb = ((size_t)(bq * 2048 + qw + qf * 16 + l15)) * 1024 + hh * 64;
#pragma unroll
        for (int dc = 0; dc < 4; ++dc) {
            bf16x4 st;
#pragma unroll
            for (int r = 0; r < 4; ++r)
                st[r] = (short)__bfloat16_as_ushort(__float2bfloat16(o[qf][dc][r] * inv));
            *(bf16x4*)(att + rowb + dc * 16 + lg * 4) = st;
        }
    }
}

// ---------------------------------------------------------------------------
extern "C" void kernel_launch(void* const* d_in, const int* in_sizes, int n_in,
                              void* d_out, int out_size, void* d_ws, size_t ws_size,
                              hipStream_t stream)
{
    const float* x    = (const float*)d_in[0];   // [2,2048,1024]
    const float* Wqkv = (const float*)d_in[1];   // [1024,3072]
    const float* bqkv = (const float*)d_in[2];   // [3072]
    const float* Wo   = (const float*)d_in[3];   // [1024,1024]
    const float* bo   = (const float*)d_in[4];   // [1024]
    float* out = (float*)d_out;                  // [2,2048,1024]

    char* ws = (char*)d_ws;
    const size_t MB = 1024 * 1024;
    __hip_bfloat16* xb    = (__hip_bfloat16*)(ws);            //  8 MB
    __hip_bfloat16* WqkvT = (__hip_bfloat16*)(ws + 8 * MB);   //  6 MB
    __hip_bfloat16* WoT   = (__hip_bfloat16*)(ws + 14 * MB);  //  2 MB
    __hip_bfloat16* Qb    = (__hip_bfloat16*)(ws + 16 * MB);  //  8 MB
    __hip_bfloat16* Kb    = (__hip_bfloat16*)(ws + 24 * MB);  //  8 MB
    __hip_bfloat16* Vt    = (__hip_bfloat16*)(ws + 32 * MB);  //  8 MB
    __hip_bfloat16* att   = (__hip_bfloat16*)(ws + 40 * MB);  //  8 MB

    k_f32_to_bf16<<<2048, 256, 0, stream>>>(x, xb, 4096 * 1024 / 4);
    k_transpose_f32_bf16<<<dim3(96, 32), 256, 0, stream>>>(Wqkv, WqkvT, 1024, 3072);
    k_transpose_f32_bf16<<<dim3(32, 32), 256, 0, stream>>>(Wo, WoT, 1024, 1024);

    k_gemm_bt<0><<<dim3(24, 32), 256, 0, stream>>>(
        xb, WqkvT, bqkv, 1024, 3072, nullptr, Qb, Kb, Vt);

    k_attn<<<512, 256, 0, stream>>>(Qb, Kb, Vt, att);

    k_gemm_bt<1><<<dim3(8, 32), 256, 0, stream>>>(
        att, WoT, bo, 1024, 1024, out, nullptr, nullptr, nullptr);
}